// Round 1
// 72.195 us; speedup vs baseline: 1.0136x; 1.0136x over previous
//
#include <hip/hip_runtime.h>
#include <hip/hip_bf16.h>

// TripletLoss B=4096 D=128 fp32. R6: symmetric-Gram triangle. The Gram is
// symmetric (g_ij == g_ji bitwise, same bf16 products + accumulation order),
// so only upper-triangle blocks (by >= bx) are launched: 528 instead of 1024.
// Each off-diagonal block mines BOTH directions from the same accumulators:
//   row path: rows i over cols j, val  = sq_j - 2g  -> partial slot by
//   col path: rows j over cols i, val' = sq_i - 2g  -> partial slot bx
// Diagonal blocks use the row path only. Coverage of the 32x4096 partial
// matrix is exact and single-writer: slot s of row-block r is written by
// block (min(r,s), max(r,s)). Everything else (pure-bf16 Gram K=128, raw
// s_barrier + fine vmcnt, LDS-fold epilogue, atomic-free partials) kept.

typedef __attribute__((ext_vector_type(8))) short short8;
typedef __attribute__((ext_vector_type(4))) float f32x4;

#define MARGIN_F 0.3f
#define NEG_BIG -3.4e38f
#define POS_BIG 3.4e38f
// gfx9 waitcnt encoding: vmcnt[3:0]|[15:14], expcnt[6:4], lgkmcnt[11:8]
#define WAITVM(N) __builtin_amdgcn_s_waitcnt(((N)&15)|((((N)>>4)&3)<<14)|(7<<4)|(15<<8))

__device__ __forceinline__ void gl_lds16(const void* g, void* l) {
    __builtin_amdgcn_global_load_lds(
        (const __attribute__((address_space(1))) void*)g,
        (__attribute__((address_space(3))) void*)l, 16, 0, 0);
}

__device__ inline unsigned short f2bf(float x) {
    union { __hip_bfloat16 h; unsigned short u; } c;
    c.h = __float2bfloat16(x);
    return c.u;
}

// grid 512 x 256: 32 threads/row. bf16 convert + row norms + zero accum.
__global__ __launch_bounds__(256) void tl_prep(const float* __restrict__ E,
                                               unsigned short* __restrict__ Ebf,
                                               float* __restrict__ sqn,
                                               unsigned* __restrict__ accum) {
    int t = blockIdx.x * 256 + threadIdx.x;
    if (t < 4) accum[t] = 0u;
    int row = t >> 5;
    int kq = (t & 31) * 4;
    float4 v = *(const float4*)&E[(size_t)row * 128 + kq];
    float s = fmaf(v.x, v.x, fmaf(v.y, v.y, fmaf(v.z, v.z, v.w * v.w)));
    ushort4 h4;
    h4.x = f2bf(v.x); h4.y = f2bf(v.y); h4.z = f2bf(v.z); h4.w = f2bf(v.w);
    *(ushort4*)&Ebf[(size_t)row * 128 + kq] = h4;
#pragma unroll
    for (int m = 1; m < 32; m <<= 1) s += __shfl_xor(s, m);
    if ((t & 31) == 0) sqn[row] = s;
}

// grid 528 x 256. 4 waves 2x2, wave tile 64x64 = 4x4 MFMA 16x16x32.
// LDS per K-chunk: 128 rows x 64 bf16, chunk c of row r at column c^(r&7).
__global__ __launch_bounds__(256, 2) void tl_phase1(const unsigned short* __restrict__ Ebf,
                                                    const int* __restrict__ labels,
                                                    const float* __restrict__ sqn,
                                                    float* __restrict__ pmp,
                                                    float* __restrict__ pmn) {
    union SM {
        struct { unsigned short A[2][128 * 64]; unsigned short B[2][128 * 64]; } s;
        struct { float mp[128][32]; float mn[128][32];
                 float mpc[128][8]; float mnc[128][8]; } f;
    };
    __shared__ __align__(16) SM sm;

    const int tid = threadIdx.x;
    const int l = tid & 63, w = tid >> 6;
    const int wr = w >> 1, wc = w & 1;
    const int q = l >> 4, r16 = l & 15;

    // upper-triangle decode: t -> (bx, by), by >= bx.
    // start(bx) = bx*(65-bx)/2; 4225-8*start(bx) = (65-2bx)^2 (exact in fp32)
    int t = (int)blockIdx.x;
    int bx = (int)((65.0f - sqrtf((float)(4225 - 8 * t))) * 0.5f);
    while (bx * (65 - bx) / 2 > t) --bx;
    while ((bx + 1) * (64 - bx) / 2 <= t) ++bx;
    const int by = bx + (t - bx * (65 - bx) / 2);
    const int i0 = bx * 128, j0 = by * 128;
    const bool diagblk = (bx == by);

    // staging sources: slot s = w*256 + t2*64 + l; row=s>>3; chunk=(s&7)^(row&7)
    const unsigned short* gA[4];
    const unsigned short* gB[4];
#pragma unroll
    for (int t2 = 0; t2 < 4; ++t2) {
        int s = w * 256 + t2 * 64 + l;
        int row = s >> 3, ch = (s & 7) ^ (row & 7);
        gA[t2] = Ebf + (size_t)(i0 + row) * 128 + ch * 8;
        gB[t2] = Ebf + (size_t)(j0 + row) * 128 + ch * 8;
    }

    // prefetch epilogue metadata early (independent of staging)
    int li[4][4], lj[4];
    float si[4][4], sj[4];
#pragma unroll
    for (int ti = 0; ti < 4; ++ti)
#pragma unroll
        for (int p = 0; p < 4; ++p) {
            int ci = i0 + wr * 64 + ti * 16 + q * 4 + p;
            li[ti][p] = labels[ci];
            si[ti][p] = sqn[ci];
        }
#pragma unroll
    for (int tj = 0; tj < 4; ++tj) {
        int cj = j0 + wc * 64 + tj * 16 + r16;
        lj[tj] = labels[cj];
        sj[tj] = sqn[cj];
    }

    // issue all staging: chunk0 (8 loads) then chunk1 (8 loads)
#pragma unroll
    for (int t2 = 0; t2 < 4; ++t2) {
        gl_lds16(gA[t2], &sm.s.A[0][w * 2048 + t2 * 512]);
        gl_lds16(gB[t2], &sm.s.B[0][w * 2048 + t2 * 512]);
    }
#pragma unroll
    for (int t2 = 0; t2 < 4; ++t2) {
        gl_lds16(gA[t2] + 64, &sm.s.A[1][w * 2048 + t2 * 512]);
        gl_lds16(gB[t2] + 64, &sm.s.B[1][w * 2048 + t2 * 512]);
    }

    f32x4 acc[4][4];
#pragma unroll
    for (int ti = 0; ti < 4; ++ti)
#pragma unroll
        for (int tj = 0; tj < 4; ++tj) acc[ti][tj] = (f32x4)0.0f;

#pragma unroll
    for (int kc = 0; kc < 2; ++kc) {
        if (kc == 0) WAITVM(8); else WAITVM(0);
        __builtin_amdgcn_s_barrier();
#pragma unroll
        for (int s = 0; s < 2; ++s) {
            short8 af[4], bf[4];
            const int cA = ((s * 4 + q) ^ (r16 & 7)) * 8;
#pragma unroll
            for (int t2 = 0; t2 < 4; ++t2) {
                af[t2] = *(const short8*)&sm.s.A[kc][(wr * 64 + t2 * 16 + r16) * 64 + cA];
                bf[t2] = *(const short8*)&sm.s.B[kc][(wc * 64 + t2 * 16 + r16) * 64 + cA];
            }
#pragma unroll
            for (int ti = 0; ti < 4; ++ti)
#pragma unroll
                for (int tj = 0; tj < 4; ++tj)
                    acc[ti][tj] = __builtin_amdgcn_mfma_f32_16x16x32_bf16(
                        af[ti], bf[tj], acc[ti][tj], 0, 0, 0);
        }
    }

    // mine both directions from the same accumulators (monotone in d2):
    //   row path (rows i over cols j): vr = sq_j - 2g
    //   col path (rows j over cols i): vc = sq_i - 2g   (skipped on diag)
    float mp[4][4], mn[4][4], mpc[4], mnc[4];
#pragma unroll
    for (int ti = 0; ti < 4; ++ti)
#pragma unroll
        for (int p = 0; p < 4; ++p) { mp[ti][p] = NEG_BIG; mn[ti][p] = POS_BIG; }
#pragma unroll
    for (int tj = 0; tj < 4; ++tj) {
        float cp = NEG_BIG, cn = POS_BIG;
#pragma unroll
        for (int ti = 0; ti < 4; ++ti)
#pragma unroll
            for (int p = 0; p < 4; ++p) {
                float g = acc[ti][tj][p];
                float vr = fmaf(-2.0f, g, sj[tj]);
                float vc = fmaf(-2.0f, g, si[ti][p]);
                bool same = (li[ti][p] == lj[tj]);
                bool self = diagblk &&
                    ((wr * 64 + ti * 16 + q * 4 + p) == (wc * 64 + tj * 16 + r16));
                mp[ti][p] = fmaxf(mp[ti][p], (same && !self) ? vr : NEG_BIG);
                mn[ti][p] = fminf(mn[ti][p], same ? POS_BIG : vr);
                cp = fmaxf(cp, (same && !self) ? vc : NEG_BIG);
                cn = fminf(cn, same ? POS_BIG : vc);
            }
        mpc[tj] = cp;
        mnc[tj] = cn;
    }

    // LDS fold: rows get 32 partials (16 col-lanes x 2 wc waves);
    // cols get 8 partials (4 q-lanes x 2 wr waves)
    __syncthreads();  // all LDS frag reads done before aliasing overwrite
#pragma unroll
    for (int ti = 0; ti < 4; ++ti)
#pragma unroll
        for (int p = 0; p < 4; ++p) {
            int rloc = wr * 64 + ti * 16 + q * 4 + p;
            sm.f.mp[rloc][wc * 16 + r16] = mp[ti][p];
            sm.f.mn[rloc][wc * 16 + r16] = mn[ti][p];
        }
#pragma unroll
    for (int tj = 0; tj < 4; ++tj) {
        int cloc = wc * 64 + tj * 16 + r16;
        sm.f.mpc[cloc][wr * 4 + q] = mpc[tj];
        sm.f.mnc[cloc][wr * 4 + q] = mnc[tj];
    }
    __syncthreads();
    {
        int row = tid >> 1, hf = tid & 1;
        const float4* P = (const float4*)&sm.f.mp[row][hf * 16];
        const float4* N = (const float4*)&sm.f.mn[row][hf * 16];
        float4 p0 = P[0], p1 = P[1], p2 = P[2], p3 = P[3];
        float4 n0 = N[0], n1 = N[1], n2 = N[2], n3 = N[3];
        float M = fmaxf(fmaxf(fmaxf(p0.x, p0.y), fmaxf(p0.z, p0.w)),
                        fmaxf(fmaxf(p1.x, p1.y), fmaxf(p1.z, p1.w)));
        M = fmaxf(M, fmaxf(fmaxf(fmaxf(p2.x, p2.y), fmaxf(p2.z, p2.w)),
                           fmaxf(fmaxf(p3.x, p3.y), fmaxf(p3.z, p3.w))));
        float m_ = fminf(fminf(fminf(n0.x, n0.y), fminf(n0.z, n0.w)),
                         fminf(fminf(n1.x, n1.y), fminf(n1.z, n1.w)));
        m_ = fminf(m_, fminf(fminf(fminf(n2.x, n2.y), fminf(n2.z, n2.w)),
                             fminf(fminf(n3.x, n3.y), fminf(n3.z, n3.w))));
        M = fmaxf(M, __shfl_xor(M, 1));
        m_ = fminf(m_, __shfl_xor(m_, 1));
        if (hf == 0) {
            pmp[(size_t)by * 4096 + i0 + row] = M;
            pmn[(size_t)by * 4096 + i0 + row] = m_;
        }
    }
    // transposed store: rows j of block by, reduced over cols i -> slot bx
    if (!diagblk && tid < 128) {
        const float4* P = (const float4*)&sm.f.mpc[tid][0];
        const float4* N = (const float4*)&sm.f.mnc[tid][0];
        float4 p0 = P[0], p1 = P[1];
        float4 n0 = N[0], n1 = N[1];
        float M = fmaxf(fmaxf(fmaxf(p0.x, p0.y), fmaxf(p0.z, p0.w)),
                        fmaxf(fmaxf(p1.x, p1.y), fmaxf(p1.z, p1.w)));
        float m_ = fminf(fminf(fminf(n0.x, n0.y), fminf(n0.z, n0.w)),
                         fminf(fminf(n1.x, n1.y), fminf(n1.z, n1.w)));
        pmp[(size_t)bx * 4096 + j0 + tid] = M;
        pmn[(size_t)bx * 4096 + j0 + tid] = m_;
    }
}

// grid 16 x 256: fold 32 partials/row, validity via LDS label hist,
// ticket-counter finalize.
__global__ __launch_bounds__(256) void tl_phase2(const int* __restrict__ labels,
                                                 const float* __restrict__ pmp,
                                                 const float* __restrict__ pmn,
                                                 const float* __restrict__ sqn,
                                                 float* __restrict__ accum,
                                                 float* __restrict__ out) {
    __shared__ unsigned hist[256];
    __shared__ float sp[4], sv[4];
    int tid = threadIdx.x;
    hist[tid] = 0u;
    __syncthreads();
#pragma unroll
    for (int k = 0; k < 16; ++k) atomicAdd(&hist[labels[k * 256 + tid]], 1u);
    __syncthreads();

    int r = blockIdx.x * 256 + tid;
    float mp = NEG_BIG, mn = POS_BIG;
#pragma unroll
    for (int k = 0; k < 32; ++k) {
        mp = fmaxf(mp, pmp[(size_t)k * 4096 + r]);
        mn = fminf(mn, pmn[(size_t)k * 4096 + r]);
    }
    float si = sqn[r];
    unsigned cnt = hist[labels[r]];
    bool valid = (cnt >= 2u) && (cnt < 4096u);
    float hp = sqrtf(fmaxf(si + mp, 0.0f));
    float hn = sqrtf(fmaxf(si + mn, 0.0f));
    float pr = fmaxf(hp - hn + MARGIN_F, 0.0f);
    float s = valid ? pr : 0.0f;
    float n = valid ? 1.0f : 0.0f;
#pragma unroll
    for (int m = 1; m < 64; m <<= 1) {
        s += __shfl_xor(s, m);
        n += __shfl_xor(n, m);
    }
    if ((tid & 63) == 0) { sp[tid >> 6] = s; sv[tid >> 6] = n; }
    __syncthreads();
    if (tid == 0) {
        float ts = sp[0] + sp[1] + sp[2] + sp[3];
        float tn = sv[0] + sv[1] + sv[2] + sv[3];
        atomicAdd(&accum[0], ts);
        atomicAdd(&accum[1], tn);
        __threadfence();
        unsigned tk = atomicAdd((unsigned*)&accum[2], 1u);
        if (tk == 15u) {
            float a = atomicAdd(&accum[0], 0.0f);
            float b = atomicAdd(&accum[1], 0.0f);
            out[0] = a / fmaxf(b, 1.0f);
        }
    }
}

extern "C" void kernel_launch(void* const* d_in, const int* in_sizes, int n_in,
                              void* d_out, int out_size, void* d_ws, size_t ws_size,
                              hipStream_t stream) {
    const float* E = (const float*)d_in[0];
    const int* labels = (const int*)d_in[1];
    float* out = (float*)d_out;

    // ws: Ebf 1 MB | pmp 512 KB | pmn 512 KB | sqn 16 KB | accum
    char* base = (char*)d_ws;
    unsigned short* Ebf = (unsigned short*)base;
    float* pmp = (float*)(base + (1u << 20));
    float* pmn = (float*)(base + (1u << 20) + (512u << 10));
    float* sqn = (float*)(base + (2u << 20));
    float* accum = (float*)(base + (2u << 20) + (16u << 10));

    tl_prep<<<512, 256, 0, stream>>>(E, Ebf, sqn, (unsigned*)accum);
    tl_phase1<<<528, 256, 0, stream>>>(Ebf, labels, sqn, pmp, pmn);
    tl_phase2<<<16, 256, 0, stream>>>(labels, pmp, pmn, sqn, accum, out);
}